// Round 10
// baseline (64.303 us; speedup 1.0000x reference)
//
#include <hip/hip_runtime.h>
#include <stdint.h>

typedef float f32x2 __attribute__((ext_vector_type(2)));
typedef float f32x4 __attribute__((ext_vector_type(4)));

#define ROWS   32
#define TILE_F (ROWS * 310)    // 9920 floats per tile
#define NTPB   8               // tiles per block
// LDS float offsets
#define XB_O    0              // x tile [32][310] + 16 pad zeros
#define W1T_O   9936           // W1 transposed [10 j][320 k], k>=310 zeroed
#define W2B_O   13136          // W2 blocked [16 s][100]: s*100 + jj*12 + k
#define W3B_O   14736          // [16 s][16]: s*16 + jj*2 + c
#define B2B_O   14992          // [128]: 8s + jj
#define CCS_O   15120          // [32][2] coeffs
#define LDSF    15184          // 60,736 B -> 2 blocks/CU, static

__device__ __forceinline__ float leaky(float v) { return fmaxf(v, 0.01f * v); }

// global->LDS direct, 16 B per lane. LDS base wave-uniform; HW adds lane*16.
__device__ __forceinline__ void gload16(const float* g, float* l) {
    auto gp = reinterpret_cast<const float __attribute__((address_space(1)))*>(
        reinterpret_cast<uintptr_t>(g));
    auto lp = reinterpret_cast<float __attribute__((address_space(3)))*>(
        reinterpret_cast<uintptr_t>(l));
    __builtin_amdgcn_global_load_lds(gp, lp, 16, 0, 0);
}

// Stage one wave-eighth of a 32-row tile: 1240 floats = 4 w16 + 216-float tail.
__device__ __forceinline__ void stage_eighth(const float* src, float* dst, int lane) {
    #pragma unroll
    for (int i = 0; i < 4; ++i) gload16(src + i * 256, dst + i * 256);
    if (lane < 54) gload16(src + 4 * 256, dst + 4 * 256);
}

__global__ __launch_bounds__(512, 4) void gen_mlp_r10(
    const float* __restrict__ x, const float* __restrict__ data_t,
    const float* __restrict__ W1, const float* __restrict__ b1,
    const float* __restrict__ W2, const float* __restrict__ b2,
    const float* __restrict__ W3, const float* __restrict__ b3,
    float* __restrict__ out)
{
    __shared__ float lds[LDSF];

    const int t     = threadIdx.x;
    const int lane  = t & 63;
    const int wq    = t >> 6;            // wave 0..7
    const int row   = t >> 4;            // 0..31: one row per 16-lane group
    const int kslot = lane & 15;         // 16 k-slots of 20 k's (zero-padded)
    const int kbase = kslot * 20;

    const int tile0 = blockIdx.x * NTPB;

    // ---- prologue: issue tile-0 staging first (latency covered by W-setup) ----
    stage_eighth(x + (size_t)tile0 * TILE_F + wq * 1240 + lane * 4,
                 lds + XB_O + wq * 1240, lane);

    // W1T [10][320] transposed; pad k in [310,320) zeroed (disjoint writes)
    for (int e = t; e < 3100; e += 512) {
        const int k = e / 10, j = e - 10 * k;
        lds[W1T_O + j * 320 + k] = W1[e];
    }
    if (t < 100) {
        const int j = t / 10, kk = t - 10 * j;
        lds[W1T_O + j * 320 + 310 + kk] = 0.f;
    }
    // W2B [16][100]: s*100 + jj*12 + k
    for (int e = t; e < 1280; e += 512) {
        const int k = e >> 7, j = e & 127;
        lds[W2B_O + (j >> 3) * 100 + (j & 7) * 12 + k] = W2[e];
    }
    if (t < 256) {   // W3B: s*16 + jj*2 + c
        const int j = t >> 1, c = t & 1;
        lds[W3B_O + (j >> 3) * 16 + (j & 7) * 2 + c] = W3[t];
    }
    if (t < 128) lds[B2B_O + t] = b2[t];
    if (t < 16)  lds[XB_O + 9920 + t] = 0.f;    // pad so s15's tail reads are finite

    asm volatile("s_waitcnt vmcnt(0) lgkmcnt(0)" ::: "memory");
    __builtin_amdgcn_s_barrier();

    #pragma unroll 1
    for (int it = 0; it < NTPB; ++it) {
        const int tile = tile0 + it;

        // ---- data_t prefetch for this tile (800 f32x4; consumed in epilogue) ----
        const f32x4* dt4 = (const f32x4*)data_t + (size_t)tile * (ROWS * 25);
        f32x4 dt0 = dt4[t];
        f32x4 dt1;
        if (t < 288) dt1 = dt4[512 + t];

        // ---- x: my row's 20-k window -> registers (only xbuf consumer) ----
        float xk[20];
        {
            const float* xr = lds + XB_O + row * 310 + kbase;
            #pragma unroll
            for (int q = 0; q < 10; ++q)
                *(f32x2*)&xk[2 * q] = *(const f32x2*)(xr + 2 * q);  // ds_read_b64
        }
        asm volatile("s_waitcnt lgkmcnt(0)" ::: "memory");
        __builtin_amdgcn_s_barrier();     // (a0): all x reads in regs -> buffer free

        // ---- stage next tile into the same buffer (async, zero VGPR) ----
        if (it + 1 < NTPB)
            stage_eighth(x + (size_t)(tile + 1) * TILE_F + wq * 1240 + lane * 4,
                         lds + XB_O + wq * 1240, lane);

        // ---- L1: 10 dots of length 20 vs W1T (per-lane LDS, b128, banks ok) ----
        float acc[10];
        #pragma unroll
        for (int j = 0; j < 10; ++j) {
            const float* wr = lds + W1T_O + j * 320 + kbase;
            f32x4 w0 = *(const f32x4*)(wr + 0);
            f32x4 w1 = *(const f32x4*)(wr + 4);
            f32x4 w2 = *(const f32x4*)(wr + 8);
            f32x4 w3_ = *(const f32x4*)(wr + 12);
            f32x4 w4 = *(const f32x4*)(wr + 16);
            float s = 0.f;
            #pragma unroll
            for (int i = 0; i < 4; ++i) s = fmaf(xk[i],      w0[i], s);
            #pragma unroll
            for (int i = 0; i < 4; ++i) s = fmaf(xk[4 + i],  w1[i], s);
            #pragma unroll
            for (int i = 0; i < 4; ++i) s = fmaf(xk[8 + i],  w2[i], s);
            #pragma unroll
            for (int i = 0; i < 4; ++i) s = fmaf(xk[12 + i], w3_[i], s);
            #pragma unroll
            for (int i = 0; i < 4; ++i) s = fmaf(xk[16 + i], w4[i], s);
            acc[j] = s;
        }
        // ---- reduce over the 16 k-slots: pure intra-wave shuffles ----
        #pragma unroll
        for (int m = 1; m < 16; m <<= 1) {
            #pragma unroll
            for (int j = 0; j < 10; ++j)
                acc[j] += __shfl_xor(acc[j], m, 64);
        }
        float h1[10];
        #pragma unroll
        for (int j = 0; j < 10; ++j) h1[j] = leaky(acc[j] + b1[j]);  // b1: s_load

        // ---- L2 (8 j's per k-slot) fused with L3; weights per-lane from LDS ----
        f32x2 p = {0.f, 0.f};
        #pragma unroll
        for (int jj = 0; jj < 8; ++jj) {
            const float* w2r = lds + W2B_O + kslot * 100 + jj * 12;
            f32x4 a = *(const f32x4*)(w2r + 0);
            f32x4 b = *(const f32x4*)(w2r + 4);
            f32x2 c = *(const f32x2*)(w2r + 8);
            float s = lds[B2B_O + kslot * 8 + jj];
            s = fmaf(h1[0], a[0], s); s = fmaf(h1[1], a[1], s);
            s = fmaf(h1[2], a[2], s); s = fmaf(h1[3], a[3], s);
            s = fmaf(h1[4], b[0], s); s = fmaf(h1[5], b[1], s);
            s = fmaf(h1[6], b[2], s); s = fmaf(h1[7], b[3], s);
            s = fmaf(h1[8], c.x, s);  s = fmaf(h1[9], c.y, s);
            s = leaky(s);
            f32x2 w3v = *(const f32x2*)(lds + W3B_O + kslot * 16 + jj * 2);
            p.x = fmaf(s, w3v.x, p.x);
            p.y = fmaf(s, w3v.y, p.y);
        }
        #pragma unroll
        for (int m = 1; m < 16; m <<= 1) {
            p.x += __shfl_xor(p.x, m, 64);
            p.y += __shfl_xor(p.y, m, 64);
        }
        if (kslot == 0) {
            f32x2 cc = {leaky(p.x + b3[0]), leaky(p.y + b3[1])};
            *(f32x2*)(lds + CCS_O + row * 2) = cc;
        }
        asm volatile("s_waitcnt lgkmcnt(0)" ::: "memory");
        __builtin_amdgcn_s_barrier();     // (c): coeffs visible

        // ---- epilogue: out = t*(c0 + c1*t), coalesced f32x4 ----
        f32x4* o4 = (f32x4*)out + (size_t)tile * (ROWS * 25);
        {
            f32x2 cc = *(const f32x2*)(lds + CCS_O + (t / 25) * 2);
            o4[t] = dt0 * (dt0 * cc.y + cc.x);
        }
        if (t < 288) {
            f32x2 cc = *(const f32x2*)(lds + CCS_O + ((512 + t) / 25) * 2);
            o4[512 + t] = dt1 * (dt1 * cc.y + cc.x);
        }

        // ---- (d): tile it+1 resident; allow the 2 stores to stay in flight ----
        if (it + 1 < NTPB) {
            asm volatile("s_waitcnt vmcnt(2)" ::: "memory");
            __builtin_amdgcn_s_barrier();
        }
    }
}

extern "C" void kernel_launch(void* const* d_in, const int* in_sizes, int n_in,
                              void* d_out, int out_size, void* d_ws, size_t ws_size,
                              hipStream_t stream) {
    const float* x      = (const float*)d_in[0];
    const float* data_t = (const float*)d_in[1];
    const float* W1     = (const float*)d_in[2];
    const float* b1     = (const float*)d_in[3];
    const float* W2     = (const float*)d_in[4];
    const float* b2     = (const float*)d_in[5];
    const float* W3     = (const float*)d_in[6];
    const float* b3     = (const float*)d_in[7];
    float* out = (float*)d_out;

    // 512 blocks x 512 threads x 8 tiles of 32 rows = 131072 rows; 2 blocks/CU
    gen_mlp_r10<<<512, 512, 0, stream>>>(x, data_t, W1, b1, W2, b2, W3, b3, out);
}